// Round 6
// baseline (537.353 us; speedup 1.0000x reference)
//
#include <hip/hip_runtime.h>

#define D_FEAT    62
#define N_CLASSES 500
#define N_DAGS    16384
#define N_NODES   48
#define MAX_PREDS 4
#define ROWB      6160               // LDS-mode outs row stride bytes: 48*64*2 + 16 pad
#define SCS_STR   49                 // scs row stride (floats)
#define HIST_ROW  64                 // shorts per history row (global mode)
#define HIST_DAG  (N_NODES * HIST_ROW)  // 3072 shorts per dag

typedef __attribute__((ext_vector_type(8))) short short8;
typedef __attribute__((ext_vector_type(4))) float f32x4;

union FragU { unsigned int u[4]; short8 v; };
struct Raw { unsigned int u[16]; };  // bf16 mode: u[0..7]; fp32 mode: u[0..15]

__device__ __forceinline__ float bf2f(unsigned short u) {
    union { unsigned int i; float f; } v;
    v.i = ((unsigned int)u) << 16;
    return v.f;
}

__device__ __forceinline__ unsigned short f2bf(float f) {
    union { float f; unsigned int i; } v;
    v.f = f;
    unsigned int x = v.i;
    return (unsigned short)((x + 0x7FFFu + ((x >> 16) & 1u)) >> 16);
}

__device__ __forceinline__ unsigned int pack2bf(float a, float b) {
    unsigned int ia = __float_as_uint(a), ib = __float_as_uint(b);
    ia += 0x7FFFu + ((ia >> 16) & 1u);
    ib += 0x7FFFu + ((ib >> 16) & 1u);
    return (ia >> 16) | (ib & 0xFFFF0000u);
}

__device__ __forceinline__ float pk_lo(unsigned int u) { return __uint_as_float(u << 16); }
__device__ __forceinline__ float pk_hi(unsigned int u) { return __uint_as_float(u & 0xFFFF0000u); }

__device__ __forceinline__ float bcast(float x, int k) {
    return __int_as_float(__builtin_amdgcn_readlane(__float_as_int(x), k));
}

__device__ __forceinline__ float ldm(const void* p, long i, int mode) {
    if (mode) return ((const float*)p)[i];
    else      return bf2f(((const unsigned short*)p)[i]);
}

// W_merge value in padded-X coords: X = [agg(62), 0,0, atom(62), 0,0]
__device__ __forceinline__ float wm_val(const void* W, int n, int k, int mode) {
    if (n >= D_FEAT) return 0.f;
    if (k < 62)  return ldm(W, n * 124 + k, mode);
    if (k < 64)  return 0.f;
    if (k < 126) return ldm(W, n * 124 + (k - 2), mode);
    return 0.f;
}

__device__ __forceinline__ float ws_val(const void* W, int n, int k, int mode) {
    if (n >= D_FEAT || k >= D_FEAT) return 0.f;
    return ldm(W, n * 62 + k, mode);
}

// Issue raw atom loads for (row) into r. NO consumption here (true prefetch).
__device__ __forceinline__ void load_raw(Raw& r, const void* atoms, long row,
                                         int quad, int mode) {
    if (mode == 0) {
        const char* base = (const char*)atoms + row * 124;
        const int off3 = (quad < 3) ? (64 + quad * 16) : 108;
        #pragma unroll
        for (int w = 0; w < 4; ++w)
            r.u[w] = *(const unsigned int*)(base + quad * 16 + 4 * w);
        #pragma unroll
        for (int w = 0; w < 4; ++w)
            r.u[4 + w] = *(const unsigned int*)(base + off3 + 4 * w);
    } else {
        const char* base = (const char*)atoms + row * 248;
        const int off3 = (quad < 3) ? (128 + quad * 32) : 216;
        #pragma unroll
        for (int w = 0; w < 4; ++w) {
            uint2 v = *(const uint2*)(base + quad * 32 + 8 * w);
            r.u[2 * w] = v.x; r.u[2 * w + 1] = v.y;
        }
        #pragma unroll
        for (int w = 0; w < 4; ++w) {
            uint2 v = *(const uint2*)(base + off3 + 8 * w);
            r.u[8 + 2 * w] = v.x; r.u[9 + 2 * w] = v.y;
        }
    }
}

__device__ __forceinline__ void pack_frags(FragU& a2, FragU& a3, const Raw& r,
                                           int quad, int mode) {
    if (mode == 0) {
        #pragma unroll
        for (int w = 0; w < 4; ++w) a2.u[w] = r.u[w];
        if (quad < 3) {
            #pragma unroll
            for (int w = 0; w < 4; ++w) a3.u[w] = r.u[4 + w];
        } else {
            a3.u[0] = r.u[5]; a3.u[1] = r.u[6]; a3.u[2] = r.u[7]; a3.u[3] = 0;
        }
    } else {
        #pragma unroll
        for (int w = 0; w < 4; ++w)
            a2.u[w] = pack2bf(__uint_as_float(r.u[2 * w]), __uint_as_float(r.u[2 * w + 1]));
        if (quad < 3) {
            #pragma unroll
            for (int w = 0; w < 4; ++w)
                a3.u[w] = pack2bf(__uint_as_float(r.u[8 + 2 * w]), __uint_as_float(r.u[9 + 2 * w]));
        } else {
            #pragma unroll
            for (int w = 0; w < 3; ++w)
                a3.u[w] = pack2bf(__uint_as_float(r.u[10 + 2 * w]), __uint_as_float(r.u[11 + 2 * w]));
            a3.u[3] = 0;
        }
    }
}

// ---------------------------------------------------------------------------
// K1: MFMA DAG scan. 1 wave/block, DPBT dags/wave.
// GH=1, DPBT=8: history in GLOBAL workspace; 2048 blocks; __launch_bounds__(64,2)
//   caps combined VGPR+AGPR <= 256/lane -> 2 waves/SIMD co-resident (TLP).
// GH=0: legacy LDS-history fallback.
// dtype mode sniffed ON DEVICE (in_sizes is dtype-invariant -> host can't tell).
// ---------------------------------------------------------------------------
template<int GH, int DPBT>
__global__ __launch_bounds__(64, 2) void k_dag(
    const void* __restrict__ atoms,
    const int*  __restrict__ preds,
    const void* __restrict__ W_single,
    const void* __restrict__ b_single,
    const void* __restrict__ W_merge,
    const void* __restrict__ b_merge,
    const void* __restrict__ att_w,
    const void* __restrict__ dag_w,
    unsigned short* __restrict__ hist,   // [N_DAGS][48][64] bf16 (GH=1 only)
    float* __restrict__ last_out,        // [D,62] fp32
    float* __restrict__ score_out)       // [D] fp32
{
    constexpr int HIST_LDS   = GH ? 0 : (DPBT * ROWB);
    constexpr int SCS_BYTES  = DPBT * SCS_STR * 4;
    constexpr int WSF_OFF    = HIST_LDS + SCS_BYTES;
    constexpr int WSF_STRIDE = 136;               // 128 B frags + 8 pad (bank spread)
    constexpr int SMEM_BYTES = WSF_OFF + 64 * WSF_STRIDE;
    __shared__ char smem[SMEM_BYTES];

    constexpr unsigned long long FULLM = (DPBT == 16) ? 0xFFFFull : 0xFFull;

    const int  lane = threadIdx.x;          // 0..63
    const int  m    = lane & 15;
    const int  quad = lane >> 4;
    const int  mc   = (DPBT == 16) ? m : (m & 7);   // dag index within the group
    const bool wq   = (DPBT == 16) || (quad < 2);   // quads holding valid C rows
    const int  d0   = blockIdx.x * DPBT;

    // dtype sniff (uniform across grid) — in_sizes can't distinguish dtypes.
    int mode;
    {
        const unsigned short* a16 = (const unsigned short*)atoms;
        const float v0 = bf2f(a16[2 * lane]);
        const float v1 = bf2f(a16[128 + 2 * lane]);
        const int bad = (!(fabsf(v0) < 64.f)) + (!(fabsf(v1) < 64.f));
        const int cnt = __popcll(__ballot(bad > 0)) + __popcll(__ballot(bad > 1));
        mode = (cnt > 16) ? 1 : 0;
    }

    // B-fragments in registers: W_merge 4nt x 4kt. W_single frags go to LDS
    // (used only on the rare single path) to cut register pressure.
    short8 wmF[4][4];
    float bm4[4], bs4[4], aw4[4], dw4[4];
    char* const wsfp = smem + WSF_OFF + lane * WSF_STRIDE;
    #pragma unroll
    for (int nt = 0; nt < 4; ++nt) {
        const int n = m + 16 * nt;
        #pragma unroll
        for (int kt = 0; kt < 4; ++kt) {
            FragU f;
            #pragma unroll
            for (int w = 0; w < 4; ++w) {
                const int k = kt * 32 + quad * 8 + 2 * w;
                f.u[w] = pack2bf(wm_val(W_merge, n, k, mode), wm_val(W_merge, n, k + 1, mode));
            }
            wmF[nt][kt] = f.v;
        }
        #pragma unroll
        for (int kt = 0; kt < 2; ++kt) {
            FragU f;
            #pragma unroll
            for (int w = 0; w < 4; ++w) {
                const int k = kt * 32 + quad * 8 + 2 * w;
                f.u[w] = pack2bf(ws_val(W_single, n, k, mode), ws_val(W_single, n, k + 1, mode));
            }
            *(short8*)(wsfp + (nt * 2 + kt) * 16) = f.v;   // per-lane LDS stash
        }
        bm4[nt] = (n < D_FEAT) ? ldm(b_merge,  n, mode) : 0.f;
        bs4[nt] = (n < D_FEAT) ? ldm(b_single, n, mode) : 0.f;
        aw4[nt] = (n < D_FEAT) ? ldm(att_w,    n, mode) : 0.f;
        dw4[nt] = (n < D_FEAT) ? ldm(dag_w,    n, mode) : 0.f;
    }

    float* scs  = (float*)(smem + HIST_LDS);
    float* srow = scs + mc * SCS_STR;
    const long arow0 = (long)(d0 + mc) * N_NODES;
    const int* pbase = preds + (size_t)(d0 + mc) * (N_NODES * MAX_PREDS);
    unsigned short* const hdag = GH ? (hist + (size_t)(d0 + mc) * HIST_DAG) : (unsigned short*)0;

    // one node's full computation (merge/single + MFMA + history/score writes)
    auto node_body = [&](int t, const int4 pv, const FragU a2, const FragU a3) {
        const int pm = max(max(pv.x, pv.y), max(pv.z, pv.w));
        const unsigned int mk = (unsigned int)(__ballot(pm >= 0) & FULLM);

        f32x4 acc[4] = { {0,0,0,0}, {0,0,0,0}, {0,0,0,0}, {0,0,0,0} };
        f32x4 sac[4] = { {0,0,0,0}, {0,0,0,0}, {0,0,0,0}, {0,0,0,0} };

        if (mk != 0u) {   // merge path
            const int p0 = pv.x, p1 = pv.y, p2 = pv.z, p3 = pv.w;
            const int c0 = max(p0, 0), c1 = max(p1, 0), c2 = max(p2, 0), c3 = max(p3, 0);
            float q0 = srow[c0], q1 = srow[c1], q2 = srow[c2], q3 = srow[c3];

            // issue the 8 history gathers FIRST so their latency overlaps the
            // softmax exp chain below.
            FragU G[2][4];
            #pragma unroll
            for (int cc = 0; cc < 2; ++cc) {
                if constexpr (GH) {
                    const unsigned short* gb = hdag + cc * 32 + quad * 8;
                    G[cc][0].v = *(const short8*)(gb + c0 * HIST_ROW);
                    G[cc][1].v = *(const short8*)(gb + c1 * HIST_ROW);
                    G[cc][2].v = *(const short8*)(gb + c2 * HIST_ROW);
                    G[cc][3].v = *(const short8*)(gb + c3 * HIST_ROW);
                } else {
                    const char* obase = smem + mc * ROWB;
                    const int boff = cc * 64 + quad * 16;
                    G[cc][0].v = *(const short8*)(obase + c0 * 128 + boff);
                    G[cc][1].v = *(const short8*)(obase + c1 * 128 + boff);
                    G[cc][2].v = *(const short8*)(obase + c2 * 128 + boff);
                    G[cc][3].v = *(const short8*)(obase + c3 * 128 + boff);
                }
            }

            q0 = (p0 >= 0) ? q0 : -1e30f;
            q1 = (p1 >= 0) ? q1 : -1e30f;
            q2 = (p2 >= 0) ? q2 : -1e30f;
            q3 = (p3 >= 0) ? q3 : -1e30f;
            const float mx = fmaxf(fmaxf(q0, q1), fmaxf(q2, q3));
            float e0 = (p0 >= 0) ? __expf(q0 - mx) : 0.f;
            float e1 = (p1 >= 0) ? __expf(q1 - mx) : 0.f;
            float e2 = (p2 >= 0) ? __expf(q2 - mx) : 0.f;
            float e3 = (p3 >= 0) ? __expf(q3 - mx) : 0.f;
            const float inv = 1.f / fmaxf(e0 + e1 + e2 + e3, 1e-30f);
            e0 *= inv; e1 *= inv; e2 *= inv; e3 *= inv;

            FragU A01[2];
            #pragma unroll
            for (int cc = 0; cc < 2; ++cc) {
                #pragma unroll
                for (int w = 0; w < 4; ++w) {
                    const float lo = fmaf(e0, pk_lo(G[cc][0].u[w]), fmaf(e1, pk_lo(G[cc][1].u[w]),
                                     fmaf(e2, pk_lo(G[cc][2].u[w]), e3 * pk_lo(G[cc][3].u[w]))));
                    const float hi = fmaf(e0, pk_hi(G[cc][0].u[w]), fmaf(e1, pk_hi(G[cc][1].u[w]),
                                     fmaf(e2, pk_hi(G[cc][2].u[w]), e3 * pk_hi(G[cc][3].u[w]))));
                    A01[cc].u[w] = pack2bf(lo, hi);
                }
            }
            #pragma unroll
            for (int nt = 0; nt < 4; ++nt) {
                f32x4 c = {0, 0, 0, 0};
                c = __builtin_amdgcn_mfma_f32_16x16x32_bf16(A01[0].v, wmF[nt][0], c, 0, 0, 0);
                c = __builtin_amdgcn_mfma_f32_16x16x32_bf16(A01[1].v, wmF[nt][1], c, 0, 0, 0);
                c = __builtin_amdgcn_mfma_f32_16x16x32_bf16(a2.v,     wmF[nt][2], c, 0, 0, 0);
                c = __builtin_amdgcn_mfma_f32_16x16x32_bf16(a3.v,     wmF[nt][3], c, 0, 0, 0);
                acc[nt] = c;
            }
        }
        if (mk != (unsigned int)FULLM) {  // single path (always at t=0, rare otherwise)
            #pragma unroll
            for (int nt = 0; nt < 4; ++nt) {
                FragU s0, s1;
                s0.v = *(const short8*)(wsfp + (nt * 2 + 0) * 16);
                s1.v = *(const short8*)(wsfp + (nt * 2 + 1) * 16);
                f32x4 c = {0, 0, 0, 0};
                c = __builtin_amdgcn_mfma_f32_16x16x32_bf16(a2.v, s0.v, c, 0, 0, 0);
                c = __builtin_amdgcn_mfma_f32_16x16x32_bf16(a3.v, s1.v, c, 0, 0, 0);
                sac[nt] = c;
            }
        }

        float out4[4][4];
        #pragma unroll
        for (int nt = 0; nt < 4; ++nt) {
            #pragma unroll
            for (int r = 0; r < 4; ++r) {
                const int dm = quad * 4 + r;
                const bool hp = (mk >> dm) & 1u;
                const float v = hp ? (acc[nt][r] + bm4[nt]) : (sac[nt][r] + bs4[nt]);
                out4[nt][r] = fmaxf(v, 0.f);
            }
        }

        // history write (bf16)
        #pragma unroll
        for (int nt = 0; nt < 4; ++nt) {
            const int n = m + 16 * nt;
            #pragma unroll
            for (int r = 0; r < 4; ++r) {
                if (wq) {
                    const int dm = quad * 4 + r;
                    if constexpr (GH)
                        hist[(size_t)(d0 + dm) * HIST_DAG + t * HIST_ROW + n] = f2bf(out4[nt][r]);
                    else
                        *(unsigned short*)(smem + dm * ROWB + t * 128 + n * 2) = f2bf(out4[nt][r]);
                }
            }
        }

        // node score (att_w; dag_w at sink), reduce over n (lane&15 within quad)
        const bool fin = (t == N_NODES - 1);
        float sr[4] = {0, 0, 0, 0};
        #pragma unroll
        for (int nt = 0; nt < 4; ++nt) {
            const float w = fin ? dw4[nt] : aw4[nt];
            #pragma unroll
            for (int r = 0; r < 4; ++r) sr[r] = fmaf(out4[nt][r], w, sr[r]);
        }
        #pragma unroll
        for (int r = 0; r < 4; ++r) {
            sr[r] += __shfl_xor(sr[r], 1);
            sr[r] += __shfl_xor(sr[r], 2);
            sr[r] += __shfl_xor(sr[r], 4);
            sr[r] += __shfl_xor(sr[r], 8);
        }
        if (m == 0 && wq) {
            #pragma unroll
            for (int r = 0; r < 4; ++r) {
                if (!fin) scs[(quad * 4 + r) * SCS_STR + t] = sr[r];
                else      score_out[d0 + quad * 4 + r] = sr[r];
            }
        }
        if (fin && wq) {
            #pragma unroll
            for (int nt = 0; nt < 4; ++nt) {
                const int n = m + 16 * nt;
                if (n < D_FEAT) {
                    #pragma unroll
                    for (int r = 0; r < 4; ++r)
                        last_out[(size_t)(d0 + quad * 4 + r) * D_FEAT + n] = out4[nt][r];
                }
            }
        }
    };

    // prime the distance-2 pipeline
    Raw r0, r1;
    load_raw(r0, atoms, arow0 + 0, quad, mode);
    int4 p0v = *(const int4*)(pbase + 0);
    load_raw(r1, atoms, arow0 + 1, quad, mode);
    int4 p1v = *(const int4*)(pbase + 4);

    #pragma unroll 1
    for (int t = 0; t < N_NODES; t += 2) {
        {   // even node: consume stage 0, refill for t+2
            const int4 p = p0v;
            FragU a2, a3;
            pack_frags(a2, a3, r0, quad, mode);
            if constexpr (!GH) {
                if (t + 2 < N_NODES) {
                    load_raw(r0, atoms, arow0 + (t + 2), quad, mode);
                    p0v = *(const int4*)(pbase + (t + 2) * 4);
                }
                node_body(t, p, a2, a3);
            } else {
                // GH: prefetch AFTER the node's history stores, so the next
                // gather's store->load wait leaves these loads younger.
                node_body(t, p, a2, a3);
                if (t + 2 < N_NODES) {
                    load_raw(r0, atoms, arow0 + (t + 2), quad, mode);
                    p0v = *(const int4*)(pbase + (t + 2) * 4);
                }
            }
        }
        {   // odd node: consume stage 1, refill for t+3
            const int4 p = p1v;
            FragU a2, a3;
            pack_frags(a2, a3, r1, quad, mode);
            if constexpr (!GH) {
                if (t + 3 < N_NODES) {
                    load_raw(r1, atoms, arow0 + (t + 3), quad, mode);
                    p1v = *(const int4*)(pbase + (t + 3) * 4);
                }
                node_body(t + 1, p, a2, a3);
            } else {
                node_body(t + 1, p, a2, a3);
                if (t + 3 < N_NODES) {
                    load_raw(r1, atoms, arow0 + (t + 3), quad, mode);
                    p1v = *(const int4*)(pbase + (t + 3) * 4);
                }
            }
        }
    }
}

// ---------------------------------------------------------------------------
// K2: per-chunk online softmax partials. chunk = 64 DAGs per wave, 256 chunks.
// ---------------------------------------------------------------------------
__global__ __launch_bounds__(256) void k_pool(
    const float* __restrict__ last,
    const float* __restrict__ score,
    float* __restrict__ vpart,    // [256,62]
    float* __restrict__ mpart,    // [256]
    float* __restrict__ spart)    // [256]
{
    const int lane = threadIdx.x & 63;
    const int wv   = threadIdx.x >> 6;
    const int c    = blockIdx.x * 4 + wv;
    const int d0   = c * 64;

    const float s = score[d0 + lane];
    float m = s;
    #pragma unroll
    for (int off = 32; off > 0; off >>= 1) m = fmaxf(m, __shfl_xor(m, off));
    const float e = __expf(s - m);
    float den = e;
    #pragma unroll
    for (int off = 32; off > 0; off >>= 1) den += __shfl_xor(den, off);

    float acc = 0.f;
    #pragma unroll 4
    for (int j = 0; j < 64; ++j) {
        const float v = (lane < D_FEAT) ? last[(size_t)(d0 + j) * D_FEAT + lane] : 0.f;
        acc = fmaf(bcast(e, j), v, acc);
    }
    if (lane < D_FEAT) vpart[c * D_FEAT + lane] = acc;
    if (lane == 0) { mpart[c] = m; spart[c] = den; }
}

// ---------------------------------------------------------------------------
// K3: combine 256 chunks (online-softmax merge) + 500-class sigmoid head.
// ---------------------------------------------------------------------------
__global__ __launch_bounds__(256) void k_final(
    const void* __restrict__ atoms,
    const float* __restrict__ vpart,
    const float* __restrict__ mpart,
    const float* __restrict__ spart,
    const void* __restrict__ W_final,
    const void* __restrict__ b_final,
    void* __restrict__ out)
{
    __shared__ float red[256];
    __shared__ float wgt[256];
    __shared__ float pooled[D_FEAT];
    const int tid = threadIdx.x;

    const unsigned short* a16 = (const unsigned short*)atoms;
    const int bad = (!(fabsf(bf2f(a16[2 * (tid & 63)])) < 64.f))
                  + (!(fabsf(bf2f(a16[128 + 2 * (tid & 63)])) < 64.f));
    red[tid] = (float)bad;
    __syncthreads();
    for (int s = 128; s > 0; s >>= 1) {
        if (tid < s) red[tid] += red[tid + s];
        __syncthreads();
    }
    const int mode = (red[0] > 64.f) ? 1 : 0;
    __syncthreads();

    const float m = mpart[tid];
    red[tid] = m;
    __syncthreads();
    for (int s = 128; s > 0; s >>= 1) {
        if (tid < s) red[tid] = fmaxf(red[tid], red[tid + s]);
        __syncthreads();
    }
    const float M = red[0];
    __syncthreads();

    const float w = __expf(m - M);
    wgt[tid] = w;
    red[tid] = w * spart[tid];
    __syncthreads();
    for (int s = 128; s > 0; s >>= 1) {
        if (tid < s) red[tid] += red[tid + s];
        __syncthreads();
    }
    const float denom = red[0];
    __syncthreads();

    if (tid < D_FEAT) {
        float acc = 0.f;
        #pragma unroll 8
        for (int c = 0; c < 256; ++c) acc = fmaf(wgt[c], vpart[c * D_FEAT + tid], acc);
        pooled[tid] = acc / denom;
    }
    __syncthreads();

    for (int r = tid; r < N_CLASSES; r += 256) {
        float acc = ldm(b_final, r, mode);
        #pragma unroll
        for (int i = 0; i < D_FEAT; ++i)
            acc = fmaf(ldm(W_final, (long)r * D_FEAT + i, mode), pooled[i], acc);
        const float sg = 1.f / (1.f + __expf(-acc));
        if (mode) ((float*)out)[r] = sg;
        else      ((unsigned short*)out)[r] = f2bf(sg);
    }
}

extern "C" void kernel_launch(void* const* d_in, const int* in_sizes, int n_in,
                              void* d_out, int out_size, void* d_ws, size_t ws_size,
                              hipStream_t stream) {
    const void* atoms    = d_in[0];
    const int*  preds    = (const int*)d_in[1];
    const void* W_single = d_in[2];
    const void* b_single = d_in[3];
    const void* W_merge  = d_in[4];
    const void* b_merge  = d_in[5];
    const void* att_w    = d_in[6];
    const void* dag_w    = d_in[7];
    const void* W_final  = d_in[8];
    const void* b_final  = d_in[9];

    float* last  = (float*)d_ws;                     // 16384*62          (3.875 MB)
    float* score = last + (size_t)N_DAGS * D_FEAT;   // 16384             (64 KB)
    float* vpart = score + N_DAGS;                   // 256*62            (62 KB)
    float* mpart = vpart + 256 * D_FEAT;             // 256
    float* spart = mpart + 256;                      // 256   -> total exactly 4 MiB
    unsigned short* hist = (unsigned short*)((char*)d_ws + (4ull << 20));
    const size_t need = (4ull << 20) + (size_t)N_DAGS * HIST_DAG * sizeof(unsigned short);
    // need = 4 MiB + 96 MiB = 104,857,600 B

    if (ws_size >= need)
        k_dag<1,8><<<N_DAGS / 8, 64, 0, stream>>>(atoms, preds, W_single, b_single,
            W_merge, b_merge, att_w, dag_w, hist, last, score);
    else
        k_dag<0,8><<<N_DAGS / 8, 64, 0, stream>>>(atoms, preds, W_single, b_single,
            W_merge, b_merge, att_w, dag_w, hist, last, score);
    k_pool <<<64, 256, 0, stream>>>(last, score, vpart, mpart, spart);
    k_final<<<1, 256, 0, stream>>>(atoms, vpart, mpart, spart, W_final, b_final, d_out);
}

// Round 7
// 490.470 us; speedup vs baseline: 1.0956x; 1.0956x over previous
//
#include <hip/hip_runtime.h>

#define D_FEAT    62
#define N_CLASSES 500
#define N_DAGS    16384
#define N_NODES   48
#define MAX_PREDS 4
#define ROWB      6160               // LDS-mode outs row stride bytes: 48*64*2 + 16 pad
#define SCS_STR   49                 // scs row stride (floats)
#define HIST_ROW  64                 // shorts per history row (global mode)
#define HIST_DAG  (N_NODES * HIST_ROW)  // 3072 shorts per dag

typedef __attribute__((ext_vector_type(8))) short short8;
typedef __attribute__((ext_vector_type(4))) float f32x4;

union FragU { unsigned int u[4]; short8 v; };
struct Raw { unsigned int u[16]; };  // bf16 mode: u[0..7]; fp32 mode: u[0..15]

__device__ __forceinline__ float bf2f(unsigned short u) {
    union { unsigned int i; float f; } v;
    v.i = ((unsigned int)u) << 16;
    return v.f;
}

__device__ __forceinline__ unsigned short f2bf(float f) {
    union { float f; unsigned int i; } v;
    v.f = f;
    unsigned int x = v.i;
    return (unsigned short)((x + 0x7FFFu + ((x >> 16) & 1u)) >> 16);
}

__device__ __forceinline__ unsigned int pack2bf(float a, float b) {
    unsigned int ia = __float_as_uint(a), ib = __float_as_uint(b);
    ia += 0x7FFFu + ((ia >> 16) & 1u);
    ib += 0x7FFFu + ((ib >> 16) & 1u);
    return (ia >> 16) | (ib & 0xFFFF0000u);
}

__device__ __forceinline__ float pk_lo(unsigned int u) { return __uint_as_float(u << 16); }
__device__ __forceinline__ float pk_hi(unsigned int u) { return __uint_as_float(u & 0xFFFF0000u); }

__device__ __forceinline__ float bcast(float x, int k) {
    return __int_as_float(__builtin_amdgcn_readlane(__float_as_int(x), k));
}

__device__ __forceinline__ float ldm(const void* p, long i, int mode) {
    if (mode) return ((const float*)p)[i];
    else      return bf2f(((const unsigned short*)p)[i]);
}

// W_merge value in padded-X coords: X = [agg(62), 0,0, atom(62), 0,0]
__device__ __forceinline__ float wm_val(const void* W, int n, int k, int mode) {
    if (n >= D_FEAT) return 0.f;
    if (k < 62)  return ldm(W, n * 124 + k, mode);
    if (k < 64)  return 0.f;
    if (k < 126) return ldm(W, n * 124 + (k - 2), mode);
    return 0.f;
}

__device__ __forceinline__ float ws_val(const void* W, int n, int k, int mode) {
    if (n >= D_FEAT || k >= D_FEAT) return 0.f;
    return ldm(W, n * 62 + k, mode);
}

// Issue raw atom loads for (row) into r. NO consumption here (true prefetch).
__device__ __forceinline__ void load_raw(Raw& r, const void* atoms, long row,
                                         int quad, int mode) {
    if (mode == 0) {
        const char* base = (const char*)atoms + row * 124;
        const int off3 = (quad < 3) ? (64 + quad * 16) : 108;
        #pragma unroll
        for (int w = 0; w < 4; ++w)
            r.u[w] = *(const unsigned int*)(base + quad * 16 + 4 * w);
        #pragma unroll
        for (int w = 0; w < 4; ++w)
            r.u[4 + w] = *(const unsigned int*)(base + off3 + 4 * w);
    } else {
        const char* base = (const char*)atoms + row * 248;
        const int off3 = (quad < 3) ? (128 + quad * 32) : 216;
        #pragma unroll
        for (int w = 0; w < 4; ++w) {
            uint2 v = *(const uint2*)(base + quad * 32 + 8 * w);
            r.u[2 * w] = v.x; r.u[2 * w + 1] = v.y;
        }
        #pragma unroll
        for (int w = 0; w < 4; ++w) {
            uint2 v = *(const uint2*)(base + off3 + 8 * w);
            r.u[8 + 2 * w] = v.x; r.u[9 + 2 * w] = v.y;
        }
    }
}

__device__ __forceinline__ void pack_frags(FragU& a2, FragU& a3, const Raw& r,
                                           int quad, int mode) {
    if (mode == 0) {
        #pragma unroll
        for (int w = 0; w < 4; ++w) a2.u[w] = r.u[w];
        if (quad < 3) {
            #pragma unroll
            for (int w = 0; w < 4; ++w) a3.u[w] = r.u[4 + w];
        } else {
            a3.u[0] = r.u[5]; a3.u[1] = r.u[6]; a3.u[2] = r.u[7]; a3.u[3] = 0;
        }
    } else {
        #pragma unroll
        for (int w = 0; w < 4; ++w)
            a2.u[w] = pack2bf(__uint_as_float(r.u[2 * w]), __uint_as_float(r.u[2 * w + 1]));
        if (quad < 3) {
            #pragma unroll
            for (int w = 0; w < 4; ++w)
                a3.u[w] = pack2bf(__uint_as_float(r.u[8 + 2 * w]), __uint_as_float(r.u[9 + 2 * w]));
        } else {
            #pragma unroll
            for (int w = 0; w < 3; ++w)
                a3.u[w] = pack2bf(__uint_as_float(r.u[10 + 2 * w]), __uint_as_float(r.u[11 + 2 * w]));
            a3.u[3] = 0;
        }
    }
}

// ---------------------------------------------------------------------------
// K1: MFMA DAG scan. 1 wave/block, DPBT dags/wave.
// GH=1, DPBT=16: 16 distinct DAGs per wave (all MFMA A-rows), history in
//   GLOBAL workspace, stores COALESCED via a 2 KB LDS transpose bounce
//   (16 scattered b16 stores -> 2 dwordx4 full-line stores per node).
// GH=0, DPBT=8: legacy LDS-history fallback.
// dtype mode sniffed ON DEVICE (in_sizes is dtype-invariant).
// ---------------------------------------------------------------------------
template<int GH, int DPBT>
__global__ __launch_bounds__(64, 1) void k_dag(
    const void* __restrict__ atoms,
    const int*  __restrict__ preds,
    const void* __restrict__ W_single,
    const void* __restrict__ b_single,
    const void* __restrict__ W_merge,
    const void* __restrict__ b_merge,
    const void* __restrict__ att_w,
    const void* __restrict__ dag_w,
    unsigned short* __restrict__ hist,   // [N_DAGS][48][64] bf16 (GH=1 only)
    float* __restrict__ last_out,        // [D,62] fp32
    float* __restrict__ score_out)       // [D] fp32
{
    constexpr int HIST_LDS   = GH ? 0 : (DPBT * ROWB);
    constexpr int SCS_BYTES  = DPBT * SCS_STR * 4;
    constexpr int WSF_OFF    = HIST_LDS + SCS_BYTES;
    constexpr int WSF_STRIDE = 136;               // 128 B frags + 8 pad (bank spread)
    constexpr int BOUNCE_OFF = WSF_OFF + 64 * WSF_STRIDE;
    constexpr int BOUNCE_SZ  = GH ? (DPBT * 128) : 0;   // [dag][64 feat] bf16
    constexpr int SMEM_BYTES = BOUNCE_OFF + (BOUNCE_SZ ? BOUNCE_SZ : 16);
    __shared__ char smem[SMEM_BYTES];

    constexpr unsigned long long FULLM = (DPBT == 16) ? 0xFFFFull : 0xFFull;

    const int  lane = threadIdx.x;          // 0..63
    const int  m    = lane & 15;
    const int  quad = lane >> 4;
    const int  mc   = (DPBT == 16) ? m : (m & 7);   // dag index within the group
    const bool wq   = (DPBT == 16) || (quad < 2);   // quads holding valid C rows
    const int  d0   = blockIdx.x * DPBT;

    // dtype sniff (uniform across grid) — in_sizes can't distinguish dtypes.
    int mode;
    {
        const unsigned short* a16 = (const unsigned short*)atoms;
        const float v0 = bf2f(a16[2 * lane]);
        const float v1 = bf2f(a16[128 + 2 * lane]);
        const int bad = (!(fabsf(v0) < 64.f)) + (!(fabsf(v1) < 64.f));
        const int cnt = __popcll(__ballot(bad > 0)) + __popcll(__ballot(bad > 1));
        mode = (cnt > 16) ? 1 : 0;
    }

    // B-fragments in registers: W_merge 4nt x 4kt. W_single frags go to LDS
    // (used only on the rare single path) to cut register pressure.
    short8 wmF[4][4];
    float bm4[4], bs4[4], aw4[4], dw4[4];
    char* const wsfp = smem + WSF_OFF + lane * WSF_STRIDE;
    #pragma unroll
    for (int nt = 0; nt < 4; ++nt) {
        const int n = m + 16 * nt;
        #pragma unroll
        for (int kt = 0; kt < 4; ++kt) {
            FragU f;
            #pragma unroll
            for (int w = 0; w < 4; ++w) {
                const int k = kt * 32 + quad * 8 + 2 * w;
                f.u[w] = pack2bf(wm_val(W_merge, n, k, mode), wm_val(W_merge, n, k + 1, mode));
            }
            wmF[nt][kt] = f.v;
        }
        #pragma unroll
        for (int kt = 0; kt < 2; ++kt) {
            FragU f;
            #pragma unroll
            for (int w = 0; w < 4; ++w) {
                const int k = kt * 32 + quad * 8 + 2 * w;
                f.u[w] = pack2bf(ws_val(W_single, n, k, mode), ws_val(W_single, n, k + 1, mode));
            }
            *(short8*)(wsfp + (nt * 2 + kt) * 16) = f.v;   // per-lane LDS stash
        }
        bm4[nt] = (n < D_FEAT) ? ldm(b_merge,  n, mode) : 0.f;
        bs4[nt] = (n < D_FEAT) ? ldm(b_single, n, mode) : 0.f;
        aw4[nt] = (n < D_FEAT) ? ldm(att_w,    n, mode) : 0.f;
        dw4[nt] = (n < D_FEAT) ? ldm(dag_w,    n, mode) : 0.f;
    }

    float* scs  = (float*)(smem + HIST_LDS);
    float* srow = scs + mc * SCS_STR;
    const long arow0 = (long)(d0 + mc) * N_NODES;
    const int* pbase = preds + (size_t)(d0 + mc) * (N_NODES * MAX_PREDS);
    unsigned short* const hdag = GH ? (hist + (size_t)(d0 + mc) * HIST_DAG) : (unsigned short*)0;

    // one node's full computation (merge/single + MFMA + history/score writes)
    auto node_body = [&](int t, const int4 pv, const FragU a2, const FragU a3) {
        const int pm = max(max(pv.x, pv.y), max(pv.z, pv.w));
        const unsigned int mk = (unsigned int)(__ballot(pm >= 0) & FULLM);

        f32x4 acc[4] = { {0,0,0,0}, {0,0,0,0}, {0,0,0,0}, {0,0,0,0} };
        f32x4 sac[4] = { {0,0,0,0}, {0,0,0,0}, {0,0,0,0}, {0,0,0,0} };

        if (mk != 0u) {   // merge path
            const int p0 = pv.x, p1 = pv.y, p2 = pv.z, p3 = pv.w;
            const int c0 = max(p0, 0), c1 = max(p1, 0), c2 = max(p2, 0), c3 = max(p3, 0);
            float q0 = srow[c0], q1 = srow[c1], q2 = srow[c2], q3 = srow[c3];

            // issue the 8 history gathers FIRST so their latency overlaps the
            // softmax exp chain below.
            FragU G[2][4];
            #pragma unroll
            for (int cc = 0; cc < 2; ++cc) {
                if constexpr (GH) {
                    const unsigned short* gb = hdag + cc * 32 + quad * 8;
                    G[cc][0].v = *(const short8*)(gb + c0 * HIST_ROW);
                    G[cc][1].v = *(const short8*)(gb + c1 * HIST_ROW);
                    G[cc][2].v = *(const short8*)(gb + c2 * HIST_ROW);
                    G[cc][3].v = *(const short8*)(gb + c3 * HIST_ROW);
                } else {
                    const char* obase = smem + mc * ROWB;
                    const int boff = cc * 64 + quad * 16;
                    G[cc][0].v = *(const short8*)(obase + c0 * 128 + boff);
                    G[cc][1].v = *(const short8*)(obase + c1 * 128 + boff);
                    G[cc][2].v = *(const short8*)(obase + c2 * 128 + boff);
                    G[cc][3].v = *(const short8*)(obase + c3 * 128 + boff);
                }
            }

            q0 = (p0 >= 0) ? q0 : -1e30f;
            q1 = (p1 >= 0) ? q1 : -1e30f;
            q2 = (p2 >= 0) ? q2 : -1e30f;
            q3 = (p3 >= 0) ? q3 : -1e30f;
            const float mx = fmaxf(fmaxf(q0, q1), fmaxf(q2, q3));
            float e0 = (p0 >= 0) ? __expf(q0 - mx) : 0.f;
            float e1 = (p1 >= 0) ? __expf(q1 - mx) : 0.f;
            float e2 = (p2 >= 0) ? __expf(q2 - mx) : 0.f;
            float e3 = (p3 >= 0) ? __expf(q3 - mx) : 0.f;
            const float inv = 1.f / fmaxf(e0 + e1 + e2 + e3, 1e-30f);
            e0 *= inv; e1 *= inv; e2 *= inv; e3 *= inv;

            FragU A01[2];
            #pragma unroll
            for (int cc = 0; cc < 2; ++cc) {
                #pragma unroll
                for (int w = 0; w < 4; ++w) {
                    const float lo = fmaf(e0, pk_lo(G[cc][0].u[w]), fmaf(e1, pk_lo(G[cc][1].u[w]),
                                     fmaf(e2, pk_lo(G[cc][2].u[w]), e3 * pk_lo(G[cc][3].u[w]))));
                    const float hi = fmaf(e0, pk_hi(G[cc][0].u[w]), fmaf(e1, pk_hi(G[cc][1].u[w]),
                                     fmaf(e2, pk_hi(G[cc][2].u[w]), e3 * pk_hi(G[cc][3].u[w]))));
                    A01[cc].u[w] = pack2bf(lo, hi);
                }
            }
            #pragma unroll
            for (int nt = 0; nt < 4; ++nt) {
                f32x4 c = {0, 0, 0, 0};
                c = __builtin_amdgcn_mfma_f32_16x16x32_bf16(A01[0].v, wmF[nt][0], c, 0, 0, 0);
                c = __builtin_amdgcn_mfma_f32_16x16x32_bf16(A01[1].v, wmF[nt][1], c, 0, 0, 0);
                c = __builtin_amdgcn_mfma_f32_16x16x32_bf16(a2.v,     wmF[nt][2], c, 0, 0, 0);
                c = __builtin_amdgcn_mfma_f32_16x16x32_bf16(a3.v,     wmF[nt][3], c, 0, 0, 0);
                acc[nt] = c;
            }
        }
        if (mk != (unsigned int)FULLM) {  // single path (always at t=0, rare otherwise)
            #pragma unroll
            for (int nt = 0; nt < 4; ++nt) {
                FragU s0, s1;
                s0.v = *(const short8*)(wsfp + (nt * 2 + 0) * 16);
                s1.v = *(const short8*)(wsfp + (nt * 2 + 1) * 16);
                f32x4 c = {0, 0, 0, 0};
                c = __builtin_amdgcn_mfma_f32_16x16x32_bf16(a2.v, s0.v, c, 0, 0, 0);
                c = __builtin_amdgcn_mfma_f32_16x16x32_bf16(a3.v, s1.v, c, 0, 0, 0);
                sac[nt] = c;
            }
        }

        float out4[4][4];
        #pragma unroll
        for (int nt = 0; nt < 4; ++nt) {
            #pragma unroll
            for (int r = 0; r < 4; ++r) {
                const int dm = quad * 4 + r;
                const bool hp = (mk >> dm) & 1u;
                const float v = hp ? (acc[nt][r] + bm4[nt]) : (sac[nt][r] + bs4[nt]);
                out4[nt][r] = fmaxf(v, 0.f);
            }
        }

        // history write (bf16)
        if constexpr (GH) {
            // transpose via LDS bounce -> coalesced wide global stores.
            char* const bounce = smem + BOUNCE_OFF;
            #pragma unroll
            for (int nt = 0; nt < 4; ++nt) {
                #pragma unroll
                for (int r = 0; r < 4; ++r)
                    *(unsigned short*)(bounce + (quad * 4 + r) * 128 + (m + 16 * nt) * 2)
                        = f2bf(out4[nt][r]);
            }
            // read back 16B/lane contiguous, 2 chunks: lanes cover DPBT dags x 128B.
            #pragma unroll
            for (int c = 0; c < DPBT / 8; ++c) {
                const int off = c * 1024 + lane * 16;
                const int dg  = off >> 7;          // dag index 0..DPBT-1
                const int ins = (off & 127) >> 1;  // short offset within row
                short8 vv = *(const short8*)(bounce + off);
                *(short8*)(hist + (size_t)(d0 + dg) * HIST_DAG + t * HIST_ROW + ins) = vv;
            }
        } else {
            #pragma unroll
            for (int nt = 0; nt < 4; ++nt) {
                const int n = m + 16 * nt;
                #pragma unroll
                for (int r = 0; r < 4; ++r) {
                    if (wq) {
                        const int dm = quad * 4 + r;
                        *(unsigned short*)(smem + dm * ROWB + t * 128 + n * 2) = f2bf(out4[nt][r]);
                    }
                }
            }
        }

        // node score (att_w; dag_w at sink), reduce over n (lane&15 within quad)
        const bool fin = (t == N_NODES - 1);
        float sr[4] = {0, 0, 0, 0};
        #pragma unroll
        for (int nt = 0; nt < 4; ++nt) {
            const float w = fin ? dw4[nt] : aw4[nt];
            #pragma unroll
            for (int r = 0; r < 4; ++r) sr[r] = fmaf(out4[nt][r], w, sr[r]);
        }
        #pragma unroll
        for (int r = 0; r < 4; ++r) {
            sr[r] += __shfl_xor(sr[r], 1);
            sr[r] += __shfl_xor(sr[r], 2);
            sr[r] += __shfl_xor(sr[r], 4);
            sr[r] += __shfl_xor(sr[r], 8);
        }
        if (m == 0 && wq) {
            #pragma unroll
            for (int r = 0; r < 4; ++r) {
                if (!fin) scs[(quad * 4 + r) * SCS_STR + t] = sr[r];
                else      score_out[d0 + quad * 4 + r] = sr[r];
            }
        }
        if (fin && wq) {
            #pragma unroll
            for (int nt = 0; nt < 4; ++nt) {
                const int n = m + 16 * nt;
                if (n < D_FEAT) {
                    #pragma unroll
                    for (int r = 0; r < 4; ++r)
                        last_out[(size_t)(d0 + quad * 4 + r) * D_FEAT + n] = out4[nt][r];
                }
            }
        }
    };

    // prime the distance-2 pipeline
    Raw r0, r1;
    load_raw(r0, atoms, arow0 + 0, quad, mode);
    int4 p0v = *(const int4*)(pbase + 0);
    load_raw(r1, atoms, arow0 + 1, quad, mode);
    int4 p1v = *(const int4*)(pbase + 4);

    #pragma unroll 1
    for (int t = 0; t < N_NODES; t += 2) {
        {   // even node: consume stage 0, refill for t+2
            const int4 p = p0v;
            FragU a2, a3;
            pack_frags(a2, a3, r0, quad, mode);
            if constexpr (!GH) {
                if (t + 2 < N_NODES) {
                    load_raw(r0, atoms, arow0 + (t + 2), quad, mode);
                    p0v = *(const int4*)(pbase + (t + 2) * 4);
                }
                node_body(t, p, a2, a3);
            } else {
                // GH: prefetch AFTER the node's history stores, so the next
                // gather's store->load wait leaves these loads younger.
                node_body(t, p, a2, a3);
                if (t + 2 < N_NODES) {
                    load_raw(r0, atoms, arow0 + (t + 2), quad, mode);
                    p0v = *(const int4*)(pbase + (t + 2) * 4);
                }
            }
        }
        {   // odd node: consume stage 1, refill for t+3
            const int4 p = p1v;
            FragU a2, a3;
            pack_frags(a2, a3, r1, quad, mode);
            if constexpr (!GH) {
                if (t + 3 < N_NODES) {
                    load_raw(r1, atoms, arow0 + (t + 3), quad, mode);
                    p1v = *(const int4*)(pbase + (t + 3) * 4);
                }
                node_body(t + 1, p, a2, a3);
            } else {
                node_body(t + 1, p, a2, a3);
                if (t + 3 < N_NODES) {
                    load_raw(r1, atoms, arow0 + (t + 3), quad, mode);
                    p1v = *(const int4*)(pbase + (t + 3) * 4);
                }
            }
        }
    }
}

// ---------------------------------------------------------------------------
// K2: per-chunk online softmax partials. chunk = 64 DAGs per wave, 256 chunks.
// ---------------------------------------------------------------------------
__global__ __launch_bounds__(256) void k_pool(
    const float* __restrict__ last,
    const float* __restrict__ score,
    float* __restrict__ vpart,    // [256,62]
    float* __restrict__ mpart,    // [256]
    float* __restrict__ spart)    // [256]
{
    const int lane = threadIdx.x & 63;
    const int wv   = threadIdx.x >> 6;
    const int c    = blockIdx.x * 4 + wv;
    const int d0   = c * 64;

    const float s = score[d0 + lane];
    float m = s;
    #pragma unroll
    for (int off = 32; off > 0; off >>= 1) m = fmaxf(m, __shfl_xor(m, off));
    const float e = __expf(s - m);
    float den = e;
    #pragma unroll
    for (int off = 32; off > 0; off >>= 1) den += __shfl_xor(den, off);

    float acc = 0.f;
    #pragma unroll 4
    for (int j = 0; j < 64; ++j) {
        const float v = (lane < D_FEAT) ? last[(size_t)(d0 + j) * D_FEAT + lane] : 0.f;
        acc = fmaf(bcast(e, j), v, acc);
    }
    if (lane < D_FEAT) vpart[c * D_FEAT + lane] = acc;
    if (lane == 0) { mpart[c] = m; spart[c] = den; }
}

// ---------------------------------------------------------------------------
// K3: combine 256 chunks (online-softmax merge) + 500-class sigmoid head.
// ---------------------------------------------------------------------------
__global__ __launch_bounds__(256) void k_final(
    const void* __restrict__ atoms,
    const float* __restrict__ vpart,
    const float* __restrict__ mpart,
    const float* __restrict__ spart,
    const void* __restrict__ W_final,
    const void* __restrict__ b_final,
    void* __restrict__ out)
{
    __shared__ float red[256];
    __shared__ float wgt[256];
    __shared__ float pooled[D_FEAT];
    const int tid = threadIdx.x;

    const unsigned short* a16 = (const unsigned short*)atoms;
    const int bad = (!(fabsf(bf2f(a16[2 * (tid & 63)])) < 64.f))
                  + (!(fabsf(bf2f(a16[128 + 2 * (tid & 63)])) < 64.f));
    red[tid] = (float)bad;
    __syncthreads();
    for (int s = 128; s > 0; s >>= 1) {
        if (tid < s) red[tid] += red[tid + s];
        __syncthreads();
    }
    const int mode = (red[0] > 64.f) ? 1 : 0;
    __syncthreads();

    const float m = mpart[tid];
    red[tid] = m;
    __syncthreads();
    for (int s = 128; s > 0; s >>= 1) {
        if (tid < s) red[tid] = fmaxf(red[tid], red[tid + s]);
        __syncthreads();
    }
    const float M = red[0];
    __syncthreads();

    const float w = __expf(m - M);
    wgt[tid] = w;
    red[tid] = w * spart[tid];
    __syncthreads();
    for (int s = 128; s > 0; s >>= 1) {
        if (tid < s) red[tid] += red[tid + s];
        __syncthreads();
    }
    const float denom = red[0];
    __syncthreads();

    if (tid < D_FEAT) {
        float acc = 0.f;
        #pragma unroll 8
        for (int c = 0; c < 256; ++c) acc = fmaf(wgt[c], vpart[c * D_FEAT + tid], acc);
        pooled[tid] = acc / denom;
    }
    __syncthreads();

    for (int r = tid; r < N_CLASSES; r += 256) {
        float acc = ldm(b_final, r, mode);
        #pragma unroll
        for (int i = 0; i < D_FEAT; ++i)
            acc = fmaf(ldm(W_final, (long)r * D_FEAT + i, mode), pooled[i], acc);
        const float sg = 1.f / (1.f + __expf(-acc));
        if (mode) ((float*)out)[r] = sg;
        else      ((unsigned short*)out)[r] = f2bf(sg);
    }
}

extern "C" void kernel_launch(void* const* d_in, const int* in_sizes, int n_in,
                              void* d_out, int out_size, void* d_ws, size_t ws_size,
                              hipStream_t stream) {
    const void* atoms    = d_in[0];
    const int*  preds    = (const int*)d_in[1];
    const void* W_single = d_in[2];
    const void* b_single = d_in[3];
    const void* W_merge  = d_in[4];
    const void* b_merge  = d_in[5];
    const void* att_w    = d_in[6];
    const void* dag_w    = d_in[7];
    const void* W_final  = d_in[8];
    const void* b_final  = d_in[9];

    float* last  = (float*)d_ws;                     // 16384*62          (3.875 MB)
    float* score = last + (size_t)N_DAGS * D_FEAT;   // 16384             (64 KB)
    float* vpart = score + N_DAGS;                   // 256*62            (62 KB)
    float* mpart = vpart + 256 * D_FEAT;             // 256
    float* spart = mpart + 256;                      // 256   -> total exactly 4 MiB
    unsigned short* hist = (unsigned short*)((char*)d_ws + (4ull << 20));
    const size_t need = (4ull << 20) + (size_t)N_DAGS * HIST_DAG * sizeof(unsigned short);
    // need = 4 MiB + 96 MiB = 104,857,600 B

    if (ws_size >= need)
        k_dag<1,16><<<N_DAGS / 16, 64, 0, stream>>>(atoms, preds, W_single, b_single,
            W_merge, b_merge, att_w, dag_w, hist, last, score);
    else
        k_dag<0,8><<<N_DAGS / 8, 64, 0, stream>>>(atoms, preds, W_single, b_single,
            W_merge, b_merge, att_w, dag_w, hist, last, score);
    k_pool <<<64, 256, 0, stream>>>(last, score, vpart, mpart, spart);
    k_final<<<1, 256, 0, stream>>>(atoms, vpart, mpart, spart, W_final, b_final, d_out);
}